// Round 11
// baseline (731.128 us; speedup 1.0000x reference)
//
#include <hip/hip_runtime.h>
#include <hip/hip_bf16.h>

typedef unsigned short u16;
typedef __attribute__((ext_vector_type(8))) short bf16x8;
typedef __attribute__((ext_vector_type(4))) float f32x4;
typedef __attribute__((ext_vector_type(16))) float f32x16;

#define NB 128
#define BANDS 30
#define HWD 15
#define NPIX 225
#define DIMC 512
#define NHEAD 8
#define HD 64
#define NSPA 226
#define NSPE 31
#define EPSF 1e-5f
#define KCONV 320     // 270 padded to multiple of 64
#define MXROWS 28928  // NB*NSPA
#define MYROWS 3968   // NB*NSPE
#define M2ROWS 32896  // MXROWS+MYROWS

__device__ __forceinline__ float b2f(u16 u) { return __uint_as_float(((unsigned)u) << 16); }
__device__ __forceinline__ u16 f2b(float f) {
  __hip_bfloat16 h = __float2bfloat16(f);
  return *reinterpret_cast<u16*>(&h);
}

#if __has_builtin(__builtin_amdgcn_global_load_lds)
#define HAVE_GLDS 1
__device__ __forceinline__ void gl_lds16(const void* g, void* l) {
  __builtin_amdgcn_global_load_lds((const __attribute__((address_space(1))) void*)g,
                                   (__attribute__((address_space(3))) void*)l, 16, 0, 0);
}
#else
#define HAVE_GLDS 0
#endif

// ---------------- consolidated weight prep ----------------
__global__ __launch_bounds__(256) void prep_k(const float* __restrict__ qkvW,
    const float* __restrict__ projW, const float* __restrict__ fc1W, const float* __restrict__ fc2W,
    const float* __restrict__ fcW, const float* __restrict__ convW,
    const float* __restrict__ g, const float* __restrict__ bb, const float* __restrict__ bm,
    const float* __restrict__ bv, const float* __restrict__ cb,
    u16* __restrict__ qkvWb, u16* __restrict__ projWb, u16* __restrict__ fc1Wb,
    u16* __restrict__ fc2Wb, u16* __restrict__ fcWb, u16* __restrict__ convWb,
    float* __restrict__ sc, float* __restrict__ sh) {
  const int S0 = 2 * 3 * DIMC * DIMC;
  const int S1 = S0 + 2 * DIMC * DIMC;
  const int S2 = S1 + 2 * DIMC * DIMC;
  const int S3 = S2 + 2 * DIMC * DIMC;
  const int S4 = S3 + DIMC * 128;
  const int S5 = S4 + DIMC * KCONV;
  const int S6 = S5 + DIMC;
  for (int i = blockIdx.x * 256 + threadIdx.x; i < S6; i += gridDim.x * 256) {
    if (i < S0) qkvWb[i] = f2b(qkvW[i]);
    else if (i < S1) { int j = i - S0; projWb[j] = f2b(projW[j]); }
    else if (i < S2) { int j = i - S1; fc1Wb[j] = f2b(fc1W[j]); }
    else if (i < S3) { int j = i - S2; fc2Wb[j] = f2b(fc2W[j]); }
    else if (i < S4) { int j = i - S3; fcWb[j] = f2b(fcW[j]); }
    else if (i < S5) {
      int j = i - S4;
      int r = j / KCONV, c = j - r * KCONV;
      convWb[j] = (c < 270) ? f2b(convW[r * 270 + c]) : (u16)0;
    } else {
      int n = i - S5;
      float inv = g[n] * rsqrtf(bv[n] + EPSF);
      sc[n] = inv;
      sh[n] = (cb[n] - bm[n]) * inv + bb[n];
    }
  }
}

// ---------------- im2col ----------------
__global__ __launch_bounds__(256) void im2col_k(const float* __restrict__ x, u16* __restrict__ Ac) {
  int idx = blockIdx.x * 256 + threadIdx.x;
  if (idx >= 28800 * 40) return;
  int m = idx / 40, g = idx - m * 40;
  int b = m / NPIX, p = m - b * NPIX;
  int i = p / 15, j = p - i * 15;
  union { u16 v[8]; uint4 u; } out;
#pragma unroll
  for (int e = 0; e < 8; e++) {
    int c = g * 8 + e;
    float v = 0.f;
    if (c < 270) {
      int band = c / 9, q = c - band * 9;
      int di = q / 3, dj = q - di * 3;
      int ii = i + di - 1, jj = j + dj - 1;
      if ((unsigned)ii < 15u && (unsigned)jj < 15u)
        v = x[((size_t)b * BANDS + band) * NPIX + ii * 15 + jj];
    }
    out.v[e] = f2b(v);
  }
  *reinterpret_cast<uint4*>(Ac + (size_t)m * KCONV + g * 8) = out.u;
}

// ---------------- CLS row init (bf16 spine) ----------------
__global__ __launch_bounds__(256) void cls_init_k(const float* __restrict__ spa_cls,
    const float* __restrict__ spe_cls, const float* __restrict__ spa_pos,
    const float* __restrict__ spe_pos, u16* __restrict__ xs, u16* __restrict__ ys) {
  int b = blockIdx.x, t = threadIdx.x;
  int d0 = t, d1 = t + 256;
  xs[(size_t)b * NSPA * DIMC + d0] = f2b(spa_cls[d0] + spa_pos[d0]);
  xs[(size_t)b * NSPA * DIMC + d1] = f2b(spa_cls[d1] + spa_pos[d1]);
  ys[(size_t)b * NSPE * DIMC + d0] = f2b(spe_cls[d0] + spe_pos[d0]);
  ys[(size_t)b * NSPE * DIMC + d1] = f2b(spe_cls[d1] + spe_pos[d1]);
}

// ------------- per-band CNN conv + BN + ReLU + mean -------------
__global__ __launch_bounds__(256) void cnn_conv_k(const float* __restrict__ x,
    const float* __restrict__ w, const float* __restrict__ cb, const float* __restrict__ g,
    const float* __restrict__ bb, const float* __restrict__ bm, const float* __restrict__ bv,
    u16* __restrict__ pooled) {
  __shared__ float img[2][NPIX];
  int b0 = blockIdx.x * 2;
  int t = threadIdx.x;
  for (int idx = t; idx < 2 * NPIX; idx += 256) ((float*)img)[idx] = x[(size_t)b0 * NPIX + idx];
  __syncthreads();
  int half = t >> 7, ch = t & 127;
  const float* im = img[half];
  float inv = g[ch] * rsqrtf(bv[ch] + EPSF);
  float beta = bb[ch] - bm[ch] * inv;
  float w9[9];
#pragma unroll
  for (int q = 0; q < 9; q++) w9[q] = w[ch * 9 + q] * inv;
  float bias = cb[ch] * inv + beta;

  float rm[15], rc[15], rp[15];
#pragma unroll
  for (int j = 0; j < 15; j++) { rm[j] = 0.f; rc[j] = im[j]; }
  float sum = 0.f;
  for (int i = 0; i < 15; i++) {
#pragma unroll
    for (int j = 0; j < 15; j++) rp[j] = (i < 14) ? im[(i + 1) * 15 + j] : 0.f;
    float a[15];
#pragma unroll
    for (int j = 0; j < 15; j++) a[j] = fmaf(w9[4], rc[j], bias);
#pragma unroll
    for (int j = 0; j < 15; j++) {
      if (j > 0)  a[j] = fmaf(w9[3], rc[j - 1], a[j]);
      if (j < 14) a[j] = fmaf(w9[5], rc[j + 1], a[j]);
      a[j] = fmaf(w9[1], rm[j], a[j]);
      if (j > 0)  a[j] = fmaf(w9[0], rm[j - 1], a[j]);
      if (j < 14) a[j] = fmaf(w9[2], rm[j + 1], a[j]);
      a[j] = fmaf(w9[7], rp[j], a[j]);
      if (j > 0)  a[j] = fmaf(w9[6], rp[j - 1], a[j]);
      if (j < 14) a[j] = fmaf(w9[8], rp[j + 1], a[j]);
    }
#pragma unroll
    for (int j = 0; j < 15; j++) sum += fmaxf(a[j], 0.f);
#pragma unroll
    for (int j = 0; j < 15; j++) { rm[j] = rc[j]; rc[j] = rp[j]; }
  }
  pooled[(size_t)(b0 + half) * 128 + ch] = f2b(sum * (1.0f / 225.0f));
}

// ---------------- LayerNorm, wave-per-row, bf16 spine in, bf16 out ----------------
template <int GATHER>
__global__ __launch_bounds__(256) void ln_v_k(const u16* __restrict__ xsc,
    const float* __restrict__ w, const float* __restrict__ bprm, u16* __restrict__ out) {
  int wid = threadIdx.x >> 6, lane = threadIdx.x & 63;
  int row = blockIdx.x * 4 + wid;
  const u16* src;
  if (GATHER) {
    if (row < MXROWS) {
      int b = row / NSPA, tk = row - b * NSPA;
      src = (tk == 0) ? xsc + ((size_t)MXROWS + (size_t)b * NSPE) * DIMC
                      : xsc + (size_t)row * DIMC;
    } else {
      int ry = row - MXROWS;
      int b = ry / NSPE, tk = ry - b * NSPE;
      src = (tk == 0) ? xsc + (size_t)b * NSPA * DIMC : xsc + (size_t)row * DIMC;
    }
  } else {
    src = xsc + (size_t)row * DIMC;
  }
  uint4 av = *reinterpret_cast<const uint4*>(src + lane * 8);
  float f[8];
  f[0] = __uint_as_float(av.x << 16); f[1] = __uint_as_float(av.x & 0xffff0000u);
  f[2] = __uint_as_float(av.y << 16); f[3] = __uint_as_float(av.y & 0xffff0000u);
  f[4] = __uint_as_float(av.z << 16); f[5] = __uint_as_float(av.z & 0xffff0000u);
  f[6] = __uint_as_float(av.w << 16); f[7] = __uint_as_float(av.w & 0xffff0000u);
  float s = 0.f, sq = 0.f;
#pragma unroll
  for (int e = 0; e < 8; e++) { s += f[e]; sq += f[e] * f[e]; }
#pragma unroll
  for (int off = 1; off <= 32; off <<= 1) { s += __shfl_xor(s, off); sq += __shfl_xor(sq, off); }
  float mean = s * (1.0f / 512.0f);
  float var = sq * (1.0f / 512.0f) - mean * mean;
  float rstd = rsqrtf(var + EPSF);
  float4 w0 = *reinterpret_cast<const float4*>(w + lane * 8);
  float4 w1 = *reinterpret_cast<const float4*>(w + lane * 8 + 4);
  float4 b0 = *reinterpret_cast<const float4*>(bprm + lane * 8);
  float4 b1 = *reinterpret_cast<const float4*>(bprm + lane * 8 + 4);
  float wv[8] = {w0.x, w0.y, w0.z, w0.w, w1.x, w1.y, w1.z, w1.w};
  float bv2[8] = {b0.x, b0.y, b0.z, b0.w, b1.x, b1.y, b1.z, b1.w};
  union { u16 v[8]; uint4 u; } r;
#pragma unroll
  for (int e = 0; e < 8; e++) r.v[e] = f2b((f[e] - mean) * rstd * wv[e] + bv2[e]);
  *reinterpret_cast<uint4*>(out + (size_t)row * DIMC + lane * 8) = r.u;
}

// ================= 128-tile MFMA GEMM, 32x32x16 core, BK=64, slot-XOR swizzle, XCD-chunked =================
// Per wave: 64x64 output = 2x2 fragments of 32x32. A/B lane map: row=l&31, k=(l>>5)*8+e.
// C/D (m74/m101-verified): col=lane&31, row=(reg&3)+8*(reg>>2)+4*(lane>>5).
// MODE 0: bf16 o1=acc+bias  MODE 1: bf16 o1=gelu  MODE 2: bf16 o1 += acc+bias (RMW spine)
// MODE 3: conv scatter -> bf16 spine  MODE 4: fc_spe scatter -> bf16 spine
// MODE 5: proj+residual-combine: non-CLS o1 += z (bf16 RMW); CLS rows -> o2 (clsprj)
template <int MODE>
__global__ __launch_bounds__(256) void mgemm_k(const u16* __restrict__ A, const u16* __restrict__ Bw,
    const float* __restrict__ bias, u16* o1, u16* o2, int M, int N, int K,
    const float* aux0, const float* aux1, const float* aux2) {
  __shared__ u16 As[128 * 64];
  __shared__ u16 Bs[128 * 64];
  const int t = threadIdx.x;
  const int wid = t >> 6, l = t & 63;
  const int wm = wid >> 1, wn = wid & 1;
  const int lr = l & 31;   // row/col within a 32x32 fragment
  const int hi = l >> 5;   // k-group (0,1)

  const int nx = gridDim.x, nwg = nx * gridDim.y;
  int hlin = blockIdx.y * nx + blockIdx.x;
  int xcd = hlin & 7, j = hlin >> 3;
  int q8 = nwg >> 3, r8 = nwg & 7;
  int L = (xcd < r8 ? xcd * (q8 + 1) : r8 * (q8 + 1) + (xcd - r8) * q8) + j;
  const int n0 = (L % nx) * 128, m0 = (L / nx) * 128;

  const int srow = l >> 3;
  const int sslot = l & 7;

  f32x16 acc[2][2];
#pragma unroll
  for (int i = 0; i < 2; i++)
#pragma unroll
    for (int j2 = 0; j2 < 2; j2++)
#pragma unroll
      for (int e = 0; e < 16; e++) acc[i][j2][e] = 0.f;

  for (int kq = 0; kq < K; kq += 64) {
#if !HAVE_GLDS
    uint4 ra[4], rb[4];
#pragma unroll
    for (int i = 0; i < 4; i++) {
      int r = wid * 32 + i * 8 + srow;
      int cg = sslot ^ (r & 7);
      ra[i] = *reinterpret_cast<const uint4*>(A + (size_t)(m0 + r) * K + kq + cg * 8);
      rb[i] = *reinterpret_cast<const uint4*>(Bw + (size_t)(n0 + r) * K + kq + cg * 8);
    }
#endif
    __syncthreads();
#if HAVE_GLDS
#pragma unroll
    for (int i = 0; i < 4; i++) {
      int r = wid * 32 + i * 8 + srow;
      int cg = sslot ^ (r & 7);
      gl_lds16(A + (size_t)(m0 + r) * K + kq + cg * 8, &As[(wid * 32 + i * 8) * 64]);
      gl_lds16(Bw + (size_t)(n0 + r) * K + kq + cg * 8, &Bs[(wid * 32 + i * 8) * 64]);
    }
#else
#pragma unroll
    for (int i = 0; i < 4; i++) {
      int r = wid * 32 + i * 8 + srow;
      *reinterpret_cast<uint4*>(&As[r * 64 + sslot * 8]) = ra[i];
      *reinterpret_cast<uint4*>(&Bs[r * 64 + sslot * 8]) = rb[i];
    }
#endif
    __syncthreads();
#pragma unroll
    for (int ks = 0; ks < 4; ks++) {
      bf16x8 af[2], bfr[2];
#pragma unroll
      for (int MI = 0; MI < 2; MI++) {
        int r = wm * 64 + MI * 32 + lr;
        af[MI] = *reinterpret_cast<const bf16x8*>(&As[r * 64 + (((ks * 2 + hi) ^ (r & 7)) << 3)]);
      }
#pragma unroll
      for (int NJ = 0; NJ < 2; NJ++) {
        int n = wn * 64 + NJ * 32 + lr;
        bfr[NJ] = *reinterpret_cast<const bf16x8*>(&Bs[n * 64 + (((ks * 2 + hi) ^ (n & 7)) << 3)]);
      }
#pragma unroll
      for (int MI = 0; MI < 2; MI++)
#pragma unroll
        for (int NJ = 0; NJ < 2; NJ++)
          acc[MI][NJ] = __builtin_amdgcn_mfma_f32_32x32x16_bf16(af[MI], bfr[NJ], acc[MI][NJ], 0, 0, 0);
    }
  }

  // epilogue: frag (MI,NJ): m = base + q + 8*g + 4*hi (reg = g*4+q), n = base + lr
#pragma unroll
  for (int MI = 0; MI < 2; MI++) {
#pragma unroll
    for (int g = 0; g < 4; g++) {
#pragma unroll
      for (int q = 0; q < 4; q++) {
        int m = m0 + wm * 64 + MI * 32 + q + 8 * g + 4 * hi;
#pragma unroll
        for (int NJ = 0; NJ < 2; NJ++) {
          int n = n0 + wn * 64 + NJ * 32 + lr;
          float v = acc[MI][NJ][g * 4 + q];
          if (MODE == 0) {
            o1[(size_t)m * N + n] = f2b(v + bias[n]);
          } else if (MODE == 1) {
            float z = v + bias[n];
            o1[(size_t)m * N + n] = f2b(0.5f * z * (1.0f + erff(z * 0.70710678118f)));
          } else if (MODE == 2) {
            size_t idx = (size_t)m * N + n;
            o1[idx] = f2b(b2f(o1[idx]) + v + bias[n]);
          } else if (MODE == 3) {
            int b = m / NPIX, p = m - b * NPIX;
            float z = fmaxf(v * aux0[n] + aux1[n], 0.f) + aux2[(size_t)(p + 1) * DIMC + n];
            o1[((size_t)b * NSPA + p + 1) * DIMC + n] = f2b(z);
          } else if (MODE == 4) {
            int b = m / BANDS, band = m - b * BANDS;
            float z = fmaxf(v + bias[n], 0.f) + aux0[(size_t)(band + 1) * DIMC + n];
            o1[((size_t)b * NSPE + band + 1) * DIMC + n] = f2b(z);
          } else if (MODE == 5) {
            float z = v + bias[n];
            int tk, sidx;
            if (m < MXROWS) {
              int b = m / NSPA; tk = m - b * NSPA; sidx = b;
            } else {
              int ry = m - MXROWS; int b = ry / NSPE; tk = ry - b * NSPE; sidx = 128 + b;
            }
            if (tk == 0) {
              o2[(size_t)sidx * DIMC + n] = f2b(z);
            } else {
              size_t idx = (size_t)m * N + n;
              o1[idx] = f2b(b2f(o1[idx]) + z);
            }
          }
        }
      }
    }
  }
}

// ---------------- CLS swap (bf16 spine) ----------------
__global__ __launch_bounds__(256) void cls_swap_k(u16* __restrict__ xsc,
                                                  const u16* __restrict__ clsprj) {
  int b = blockIdx.x, t = threadIdx.x;
  size_t xrow = (size_t)b * NSPA * DIMC;
  size_t yrow = ((size_t)MXROWS + (size_t)b * NSPE) * DIMC;
#pragma unroll
  for (int q = 0; q < 2; q++) {
    int d = t + q * 256;
    xsc[xrow + d] = f2b(2.0f * b2f(xsc[xrow + d]) + b2f(clsprj[(size_t)(128 + b) * DIMC + d]));
    xsc[yrow + d] = f2b(2.0f * b2f(xsc[yrow + d]) + b2f(clsprj[(size_t)b * DIMC + d]));
  }
}

// ================= V transpose, both streams in one launch =================
__global__ __launch_bounds__(256) void vt2_k(const u16* __restrict__ qkv_spa,
    const u16* __restrict__ qkv_spe, u16* __restrict__ vtx, u16* __restrict__ vty) {
  __shared__ u16 Vl[64 * 72];
  int h = blockIdx.x, b = blockIdx.y, strm = blockIdx.z;
  int NTOK = strm ? NSPE : NSPA;
  int KP = strm ? 64 : 256;
  int t = threadIdx.x;
  const size_t rs = 3 * DIMC;
  const u16* src = (strm ? qkv_spe : qkv_spa) + (size_t)b * NTOK * rs + 2 * DIMC + h * HD;
  u16* dst = (strm ? vty : vtx) + (size_t)(b * NHEAD + h) * HD * KP;
  for (int kt = 0; kt < KP / 64; kt++) {
    __syncthreads();
#pragma unroll
    for (int p = 0; p < 2; p++) {
      int idx = p * 256 + t;
      int row = idx >> 3, c = idx & 7;
      int tok = kt * 64 + row;
      uint4 v = make_uint4(0, 0, 0, 0);
      if (tok < NTOK) v = *reinterpret_cast<const uint4*>(src + (size_t)tok * rs + c * 8);
      *reinterpret_cast<uint4*>(&Vl[row * 72 + c * 8]) = v;
    }
    __syncthreads();
    int d = t & 63, tg = t >> 6;
    unsigned pu[8];
#pragma unroll
    for (int i = 0; i < 8; i++) {
      unsigned a = Vl[(tg * 16 + 2 * i) * 72 + d];
      unsigned bb2 = Vl[(tg * 16 + 2 * i + 1) * 72 + d];
      pu[i] = (bb2 << 16) | a;
    }
    uint4 o0 = make_uint4(pu[0], pu[1], pu[2], pu[3]);
    uint4 o1 = make_uint4(pu[4], pu[5], pu[6], pu[7]);
    u16* dp = dst + (size_t)d * KP + kt * 64 + tg * 16;
    *reinterpret_cast<uint4*>(dp) = o0;
    *reinterpret_cast<uint4*>(dp + 8) = o1;
  }
}

// ================= shared helpers for flash =================
__device__ __forceinline__ int fsw(int row, int chunk) {
  return row * 64 + ((chunk ^ (row & 7)) << 3);
}
__device__ __forceinline__ void stage64(const u16* __restrict__ gsrc, size_t gstride,
                                        u16* lds, int w, int l) {
#pragma unroll
  for (int i = 0; i < 2; i++) {
    int r = w * 16 + i * 8 + (l >> 3);
    int c = l & 7;
    int scg = c ^ (r & 7);
    const u16* g = gsrc + (size_t)r * gstride + scg * 8;
#if HAVE_GLDS
    gl_lds16(g, &lds[(w * 16 + i * 8) * 64]);
#else
    *reinterpret_cast<uint4*>(&lds[r * 64 + c * 8]) = *reinterpret_cast<const uint4*>(g);
#endif
  }
}

// ================= flashq: spa attention, wave owns a 64-row q-tile =================
__global__ __launch_bounds__(256) void flashq_k(const u16* __restrict__ qkv,
    const u16* __restrict__ vt, u16* __restrict__ o, int N, int kpad, float scale) {
  __shared__ u16 Qs[4][64 * 64];
  __shared__ u16 KV[2][64 * 64];
  u16* Ks = KV[0];
  u16* Vs = KV[1];
  u16* Ol = KV[0];
  const int h = blockIdx.x, b = blockIdx.y;
  const int t = threadIdx.x;
  const int w = t >> 6, l = t & 63;
  const int lr = l & 15, lk = l >> 4;
  const size_t rs = 3 * DIMC;
  const size_t qbase = (size_t)b * N * rs + h * HD;
  const u16* vbase = vt + (size_t)(b * NHEAD + h) * HD * kpad;

#pragma unroll
  for (int i = 0; i < 8; i++) {
    int r = i * 8 + (l >> 3);
    int c = l & 7;
    int scg = c ^ (r & 7);
    const u16* g = qkv + qbase + (size_t)(w * 64 + r) * rs + scg * 8;
#if HAVE_GLDS
    gl_lds16(g, &Qs[w][(i * 8) * 64]);
#else
    *reinterpret_cast<uint4*>(&Qs[w][r * 64 + c * 8]) = *reinterpret_cast<const uint4*>(g);
#endif
  }
  __syncthreads();
  bf16x8 bq[4][2];
#pragma unroll
  for (int nj = 0; nj < 4; nj++) {
    bq[nj][0] = *reinterpret_cast<const bf16x8*>(&Qs[w][fsw(nj * 16 + lr, lk)]);
    bq[nj][1] = *reinterpret_cast<const bf16x8*>(&Qs[w][fsw(nj * 16 + lr, 4 + lk)]);
  }

  float m_i[4], l_i[4];
  f32x4 oacc[4][4];
#pragma unroll
  for (int nj = 0; nj < 4; nj++) { m_i[nj] = -1e30f; l_i[nj] = 0.f; }
#pragma unroll
  for (int mi = 0; mi < 4; mi++)
#pragma unroll
    for (int nj = 0; nj < 4; nj++) oacc[mi][nj] = (f32x4){0.f, 0.f, 0.f, 0.f};

  const int nkt = kpad >> 6;
  for (int kt = 0; kt < nkt; kt++) {
    __syncthreads();
    stage64(qkv + qbase + DIMC + (size_t)(kt * 64) * rs, rs, Ks, w, l);
    stage64(vbase + kt * 64, (size_t)kpad, Vs, w, l);
    __syncthreads();

#pragma unroll
    for (int nj = 0; nj < 4; nj++) {
      f32x4 st[4];
#pragma unroll
      for (int mi = 0; mi < 4; mi++) st[mi] = (f32x4){0.f, 0.f, 0.f, 0.f};
      __builtin_amdgcn_s_setprio(1);
#pragma unroll
      for (int mi = 0; mi < 4; mi++) {
        bf16x8 ak0 = *reinterpret_cast<const bf16x8*>(&Ks[fsw(mi * 16 + lr, lk)]);
        bf16x8 ak1 = *reinterpret_cast<const bf16x8*>(&Ks[fsw(mi * 16 + lr, 4 + lk)]);
        st[mi] = __builtin_amdgcn_mfma_f32_16x16x32_bf16(ak0, bq[nj][0], st[mi], 0, 0, 0);
        st[mi] = __builtin_amdgcn_mfma_f32_16x16x32_bf16(ak1, bq[nj][1], st[mi], 0, 0, 0);
      }
      __builtin_amdgcn_s_setprio(0);

      float sv[4][4];
      float tmax = -1e30f;
#pragma unroll
      for (int mi = 0; mi < 4; mi++)
#pragma unroll
        for (int q = 0; q < 4; q++) {
          int kgl = kt * 64 + mi * 16 + lk * 4 + q;
          float v = (kgl < N) ? st[mi][q] * scale : -1e30f;
          sv[mi][q] = v;
          tmax = fmaxf(tmax, v);
        }
      tmax = fmaxf(tmax, __shfl_xor(tmax, 16));
      tmax = fmaxf(tmax, __shfl_xor(tmax, 32));
      float mn = fmaxf(m_i[nj], tmax);
      float corr = __expf(m_i[nj] - mn);
      m_i[nj] = mn;
      float rsum = 0.f;
#pragma unroll
      for (int mi = 0; mi < 4; mi++)
#pragma unroll
        for (int q = 0; q < 4; q++) {
          float p = __expf(sv[mi][q] - mn);
          sv[mi][q] = p;
          rsum += p;
        }
      rsum += __shfl_xor(rsum, 16);
      rsum += __shfl_xor(rsum, 32);
      l_i[nj] = l_i[nj] * corr + rsum;
#pragma unroll
      for (int mi = 0; mi < 4; mi++) oacc[mi][nj] *= corr;

      unsigned pk[4][2];
#pragma unroll
      for (int mi = 0; mi < 4; mi++) {
        pk[mi][0] = ((unsigned)f2b(sv[mi][1]) << 16) | (unsigned)f2b(sv[mi][0]);
        pk[mi][1] = ((unsigned)f2b(sv[mi][3]) << 16) | (unsigned)f2b(sv[mi][2]);
      }
      int src0 = lr + 32 * (lk & 1);
      int src1 = src0 + 16;
      bool hi = lk >= 2;
      bf16x8 pbv[2];
#pragma unroll
      for (int c = 0; c < 2; c++) {
        unsigned a0 = __shfl(pk[2 * c][0], src0), b0 = __shfl(pk[2 * c + 1][0], src0);
        unsigned a1 = __shfl(pk[2 * c][1], src0), b1 = __shfl(pk[2 * c + 1][1], src0);
        unsigned a2 = __shfl(pk[2 * c][0], src1), b2 = __shfl(pk[2 * c + 1][0], src1);
        unsigned a3 = __shfl(pk[2 * c][1], src1), b3 = __shfl(pk[2 * c + 1][1], src1);
        union { unsigned u[4]; bf16x8 v; } pu;
        pu.u[0] = hi ? b0 : a0;
        pu.u[1] = hi ? b1 : a1;
        pu.u[2] = hi ? b2 : a2;
        pu.u[3] = hi ? b3 : a3;
        pbv[c] = pu.v;
      }

      __builtin_amdgcn_s_setprio(1);
#pragma unroll
      for (int mi = 0; mi < 4; mi++) {
        bf16x8 av0 = *reinterpret_cast<const bf16x8*>(&Vs[fsw(mi * 16 + lr, lk)]);
        bf16x8 av1 = *reinterpret_cast<const bf16x8*>(&Vs[fsw(mi * 16 + lr, 4 + lk)]);
        oacc[mi][nj] = __builtin_amdgcn_mfma_f32_16x16x32_bf16(av0, pbv[0], oacc[mi][nj], 0, 0, 0);
        oacc[mi][nj] = __builtin_amdgcn_mfma_f32_16x16x32_bf16(av1, pbv[1], oacc[mi][nj], 0, 0, 0);
      }
      __builtin_amdgcn_s_setprio(0);
    }
  }

  float invl[4];
#pragma unroll
  for (int nj = 0; nj < 4; nj++) invl[nj] = 1.0f / l_i[nj];
  for (int pass = 0; pass < 4; pass++) {
    __syncthreads();
    if (w == pass) {
#pragma unroll
      for (int mi = 0; mi < 4; mi++)
#pragma unroll
        for (int nj = 0; nj < 4; nj++) {
          unsigned lo = ((unsigned)f2b(oacc[mi][nj][1] * invl[nj]) << 16) |
                        (unsigned)f2b(oacc[mi][nj][0] * invl[nj]);
          unsigned hi2 = ((unsigned)f2b(oacc[mi][nj][3] * invl[nj]) << 16) |
                         (unsigned)f2b(oacc[mi][nj][2] * invl[nj]);
          uint2 pr; pr.x = lo; pr.y = hi2;
          *reinterpret_cast<uint2*>(&Ol[(nj * 16 + lr) * 72 + mi * 16 + lk * 4]) = pr;
        }
    }
    __syncthreads();
    int row = t >> 2, c4 = t & 3;
    int qrow = pass * 64 + row;
    if (qrow < N) {
      uint4 v0 = *reinterpret_cast<const uint4*>(&Ol[row * 72 + c4 * 8]);
      uint4 v1 = *reinterpret_cast<const uint4*>(&Ol[row * 72 + (c4 + 4) * 8]);
      u16* op = o + ((size_t)b * N + qrow) * DIMC + h * HD;
      *reinterpret_cast<uint4*>(op + c4 * 8) = v0;
      *reinterpret_cast<uint4*>(op + (c4 + 4) * 8) = v1;
    }
  }
}

// ================= flashm: spe attention =================
__global__ __launch_bounds__(256) void flashm_k(const u16* __restrict__ qkv,
    const u16* __restrict__ vt, u16* __restrict__ o, int N, int kpad, float scale) {
  __shared__ u16 Qs[64 * 64], Ks[64 * 64], Vs[64 * 64];
  __shared__ u16 Ol[64 * 72];
  const int qt = blockIdx.x, h = blockIdx.y, b = blockIdx.z;
  const int t = threadIdx.x;
  const int w = t >> 6, l = t & 63;
  const int lr = l & 15, lk = l >> 4;
  const size_t rs = 3 * DIMC;
  const size_t qbase = (size_t)b * N * rs + h * HD;
  const u16* vbase = vt + (size_t)(b * NHEAD + h) * HD * kpad;

  stage64(qkv + qbase + (size_t)(qt * 64) * rs, rs, Qs, w, l);
  __syncthreads();
  bf16x8 bq0 = *reinterpret_cast<const bf16x8*>(&Qs[fsw(w * 16 + lr, lk)]);
  bf16x8 bq1 = *reinterpret_cast<const bf16x8*>(&Qs[fsw(w * 16 + lr, 4 + lk)]);

  float m_i = -1e30f, l_i = 0.f;
  f32x4 oacc[4];
#pragma unroll
  for (int mi = 0; mi < 4; mi++) oacc[mi] = (f32x4){0.f, 0.f, 0.f, 0.f};

  const int nkt = (kpad + 63) >> 6;
  for (int kt = 0; kt < nkt; kt++) {
    __syncthreads();
    stage64(qkv + qbase + DIMC + (size_t)(kt * 64) * rs, rs, Ks, w, l);
    stage64(vbase + kt * 64, (size_t)kpad, Vs, w, l);
    __syncthreads();

    f32x4 st[4];
#pragma unroll
    for (int mi = 0; mi < 4; mi++) st[mi] = (f32x4){0.f, 0.f, 0.f, 0.f};
#pragma unroll
    for (int mi = 0; mi < 4; mi++) {
      bf16x8 ak0 = *reinterpret_cast<const bf16x8*>(&Ks[fsw(mi * 16 + lr, lk)]);
      bf16x8 ak1 = *reinterpret_cast<const bf16x8*>(&Ks[fsw(mi * 16 + lr, 4 + lk)]);
      st[mi] = __builtin_amdgcn_mfma_f32_16x16x32_bf16(ak0, bq0, st[mi], 0, 0, 0);
      st[mi] = __builtin_amdgcn_mfma_f32_16x16x32_bf16(ak1, bq1, st[mi], 0, 0, 0);
    }

    float sv[4][4];
    float tmax = -1e30f;
#pragma unroll
    for (int mi = 0; mi < 4; mi++)
#pragma unroll
      for (int q = 0; q < 4; q++) {
        int kgl = kt * 64 + mi * 16 + lk * 4 + q;
        float v = (kgl < N) ? st[mi][q] * scale : -1e30f;
        sv[mi][q] = v;
        tmax = fmaxf(tmax, v);
      }
    tmax = fmaxf(tmax, __shfl_xor(tmax, 16));
    tmax = fmaxf(tmax, __shfl_xor(tmax, 32));
    float mn = fmaxf(m_i, tmax);
    float corr = __expf(m_i - mn);
    m_i = mn;
    float rsum = 0.f;
#pragma unroll
    for (int mi = 0; mi < 4; mi++)
#pragma unroll
      for (int q = 0; q < 4; q++) {
        float p = __expf(sv[mi][q] - mn);
        sv[mi][q] = p;
        rsum += p;
      }
    rsum += __shfl_xor(rsum, 16);
    rsum += __shfl_xor(rsum, 32);
    l_i = l_i * corr + rsum;
#pragma unroll
    for (int mi = 0; mi < 4; mi++) oacc[mi] *= corr;

    unsigned pk[4][2];
#pragma unroll
    for (int mi = 0; mi < 4; mi++) {
      pk[mi][0] = ((unsigned)f2b(sv[mi][1]) << 16) | (unsigned)f2b(sv[mi][0]);
      pk[mi][1] = ((unsigned)f2b(sv[mi][3]) << 16) | (unsigned)f2b(sv[mi][2]);
    }
    int src0 = lr + 32 * (lk & 1);
    int src1 = src0 + 16;
    bool hi = lk >= 2;
    bf16x8 pbv[2];
#pragma unroll
    for (int c = 0; c < 2; c++) {
      unsigned a0 = __shfl(pk[2 * c][0], src0), b0 = __shfl(pk[2 * c + 1][0], src0);
      unsigned a1 = __shfl(pk[2 * c][1], src0), b1 = __shfl(pk[2 * c + 1][1], src0);
      unsigned a2 = __shfl(pk[2 * c][0], src1), b2 = __shfl(pk[2 * c + 1][0], src1);
      unsigned a3 = __shfl(pk[2 * c][1], src1), b3 = __shfl(pk[2 * c + 1][1], src1);
      union { unsigned u[4]; bf16x8 v; } pu;
      pu.u[0] = hi ? b0 : a0;
      pu.u[1] = hi ? b1 : a1;
      pu.u[2] = hi ? b2 : a2;
      pu.u[3] = hi ? b3 : a3;
      pbv[c] = pu.v;
    }

#pragma unroll
    for (int mi = 0; mi < 4; mi++) {
      bf16x8 av0 = *reinterpret_cast<const bf16x8*>(&Vs[fsw(mi * 16 + lr, lk)]);
      bf16x8 av1 = *reinterpret_cast<const bf16x8*>(&Vs[fsw(mi * 16 + lr, 4 + lk)]);
      oacc[mi] = __builtin_amdgcn_mfma_f32_16x16x32_bf16(av0, pbv[0], oacc[mi], 0, 0, 0);
      oacc[mi] = __builtin_amdgcn_mfma_f32_16x16x32_bf16(av1, pbv[1], oacc[mi], 0, 0, 0);
    }
  }

  float invl = 1.0f / l_i;
#pragma unroll
  for (int mi = 0; mi < 4; mi++) {
    unsigned lo = ((unsigned)f2b(oacc[mi][1] * invl) << 16) | (unsigned)f2b(oacc[mi][0] * invl);
    unsigned hi2 = ((unsigned)f2b(oacc[mi][3] * invl) << 16) | (unsigned)f2b(oacc[mi][2] * invl);
    uint2 pr; pr.x = lo; pr.y = hi2;
    *reinterpret_cast<uint2*>(&Ol[(w * 16 + lr) * 72 + mi * 16 + lk * 4]) = pr;
  }
  __syncthreads();
  {
    int row = t >> 2, c4 = t & 3;
    int qrow = qt * 64 + row;
    if (qrow < N) {
      uint4 v0 = *reinterpret_cast<const uint4*>(&Ol[row * 72 + c4 * 8]);
      uint4 v1 = *reinterpret_cast<const uint4*>(&Ol[row * 72 + (c4 + 4) * 8]);
      u16* op = o + ((size_t)b * N + qrow) * DIMC + h * HD;
      *reinterpret_cast<uint4*>(op + c4 * 8) = v0;
      *reinterpret_cast<uint4*>(op + (c4 + 4) * 8) = v1;
    }
  }
}

// ---------------- fused final LN (CLS tokens, bf16 spine) + head ----------------
__global__ __launch_bounds__(256) void lnhead_k(const u16* __restrict__ xsc,
    const u16* __restrict__ ysb, const float* __restrict__ w1, const float* __restrict__ b1,
    const float* __restrict__ w2, const float* __restrict__ b2, const float* __restrict__ hw,
    const float* __restrict__ hb, float* __restrict__ out) {
  __shared__ float cl[1024];
  __shared__ float sa[4], sb4[4];
  __shared__ float part[256];
  int b = blockIdx.x, t = threadIdx.x;
  int wid = t >> 6;
  for (int half = 0; half < 2; half++) {
    const u16* src = half ? (ysb + (size_t)b * NSPE * DIMC) : (xsc + (size_t)b * NSPA * DIMC);
    const float* w = half ? w2 : w1;
    const float* bp = half ? b2 : b1;
    float x0 = b2f(src[t]), x1 = b2f(src[t + 256]);
    float s = x0 + x1, sq = x0 * x0 + x1 * x1;
    for (int off = 32; off; off >>= 1) { s += __shfl_down(s, off); sq += __shfl_down(sq, off); }
    if ((t & 63) == 0) { sa[wid] = s; sb4[wid] = sq; }
    __syncthreads();
    s = sa[0] + sa[1] + sa[2] + sa[3];
    sq = sb4[0] + sb4[1] + sb4[2] + sb4[3];
    float mean = s * (1.0f / 512.0f);
    float var = sq * (1.0f / 512.0f) - mean * mean;
    float rstd = rsqrtf(var + EPSF);
    cl[half * DIMC + t] = (x0 - mean) * rstd * w[t] + bp[t];
    cl[half * DIMC + t + 256] = (x1 - mean) * rstd * w[t + 256] + bp[t + 256];
    __syncthreads();
  }
  int c = t >> 4, sl = t & 15;
  float p = 0.f;
  for (int j = 0; j < 64; j++) p += cl[sl * 64 + j] * hw[(size_t)c * 1024 + sl * 64 + j];
  part[t] = p;
  __syncthreads();
  if (sl == 0) {
    float sum = hb[c];
    for (int q = 0; q < 16; q++) sum += part[c * 16 + q];
    out[(size_t)b * 16 + c] = sum;
  }
}

extern "C" void kernel_launch(void* const* d_in, const int* in_sizes, int n_in,
                              void* d_out, int out_size, void* d_ws, size_t ws_size,
                              hipStream_t stream) {
  const float* x        = (const float*)d_in[0];
  const float* conv_h_w = (const float*)d_in[1];
  const float* conv_h_b = (const float*)d_in[2];
  const float* bn_h_g   = (const float*)d_in[3];
  const float* bn_h_b   = (const float*)d_in[4];
  const float* bn_h_m   = (const float*)d_in[5];
  const float* bn_h_v   = (const float*)d_in[6];
  const float* cnn_conv_w = (const float*)d_in[7];
  const float* cnn_conv_b = (const float*)d_in[8];
  const float* cnn_bn_g = (const float*)d_in[9];
  const float* cnn_bn_b = (const float*)d_in[10];
  const float* cnn_bn_m = (const float*)d_in[11];
  const float* cnn_bn_v = (const float*)d_in[12];
  const float* cnn_fc_w = (const float*)d_in[13];
  const float* cnn_fc_b = (const float*)d_in[14];
  const float* spa_cls  = (const float*)d_in[15];
  const float* spe_cls  = (const float*)d_in[16];
  const float* spa_pos  = (const float*)d_in[17];
  const float* spe_pos  = (const float*)d_in[18];
  const float* blk_n1_w = (const float*)d_in[19];
  const float* blk_n1_b = (const float*)d_in[20];
  const float* blk_n2_w = (const float*)d_in[21];
  const float* blk_n2_b = (const float*)d_in[22];
  const float* blk_qkv_w = (const float*)d_in[23];
  const float* blk_qkv_b = (const float*)d_in[24];
  const float* blk_proj_w = (const float*)d_in[25];
  const float* blk_proj_b = (const float*)d_in[26];
  const float* blk_fc1_w = (const float*)d_in[27];
  const float* blk_fc1_b = (const float*)d_in[28];
  const float* blk_fc2_w = (const float*)d_in[29];
  const float* blk_fc2_b = (const float*)d_in[30];
  const float* norm1_w  = (const float*)d_in[31];
  const float* norm1_b  = (const float*)d_in[32];
  const float* norm2_w  = (const float*)d_in[33];
  const float* norm2_b  = (const float*)d_in[34];
  const float* head_w   = (const float*)d_in[35];
  const float* head_b   = (const float*)d_in[36];

  char* ws = (char*)d_ws;
  size_t off = 0;
  auto take = [&](size_t bytes) -> char* {
    char* p = ws + off;
    off = (off + bytes + 255) & ~(size_t)255;
    return p;
  };
  const int Mx = MXROWS, M2 = M2ROWS;
  const int Mc = NB * NPIX;   // 28800
  const int Mf = NB * BANDS;  // 3840
  u16* xsc    = (u16*)take((size_t)M2 * DIMC * 2);      // bf16 residual spine (xs||ys)
  u16* ysb    = xsc + (size_t)Mx * DIMC;
  u16* xyin   = (u16*)take((size_t)M2 * DIMC * 2);      // LN out; vtx overlays during attention
  u16* qkvxy  = (u16*)take((size_t)M2 * 3 * DIMC * 2);
  u16* oxy    = (u16*)take((size_t)M2 * DIMC * 2);
  u16* clsprj = (u16*)take((size_t)256 * DIMC * 2);
  u16* pooled = (u16*)take((size_t)Mf * 128 * 2);
  u16* qkvWb  = (u16*)take((size_t)2 * 3 * DIMC * DIMC * 2);
  u16* projWb = (u16*)take((size_t)2 * DIMC * DIMC * 2);
  u16* fc1Wb  = (u16*)take((size_t)2 * DIMC * DIMC * 2);
  u16* fc2Wb  = (u16*)take((size_t)2 * DIMC * DIMC * 2);
  u16* fcWb   = (u16*)take((size_t)DIMC * 128 * 2);
  u16* convWb = (u16*)take((size_t)DIMC * KCONV * 2);
  float* bnsc = (float*)take(DIMC * 4);
  float* bnsh = (float*)take(DIMC * 4);
  u16* vty    = (u16*)take((size_t)NB * NHEAD * HD * 64 * 2);  // 8.4MB
  u16* Acol   = qkvxy;   // 18.4MB << qkvxy
  u16* vtx    = xyin;    // 33.55MB <= xyin; xyin dead between qkv-GEMM and LN2

  // ---- weight prep (single consolidated launch) ----
  prep_k<<<2048, 256, 0, stream>>>(blk_qkv_w, blk_proj_w, blk_fc1_w, blk_fc2_w, cnn_fc_w,
      conv_h_w, bn_h_g, bn_h_b, bn_h_m, bn_h_v, conv_h_b,
      qkvWb, projWb, fc1Wb, fc2Wb, fcWb, convWb, bnsc, bnsh);

  // ---- stem ----
  cls_init_k<<<NB, 256, 0, stream>>>(spa_cls, spe_cls, spa_pos, spe_pos, xsc, ysb);
  im2col_k<<<(Mc * 40 + 255) / 256, 256, 0, stream>>>(x, Acol);
  mgemm_k<3><<<dim3(4, Mc / 128), 256, 0, stream>>>(Acol, convWb, nullptr, xsc, nullptr,
      Mc, DIMC, KCONV, bnsc, bnsh, spa_pos);
  cnn_conv_k<<<Mf / 2, 256, 0, stream>>>(x, cnn_conv_w, cnn_conv_b, cnn_bn_g, cnn_bn_b,
                                         cnn_bn_m, cnn_bn_v, pooled);
  mgemm_k<4><<<dim3(4, Mf / 128), 256, 0, stream>>>(pooled, fcWb, cnn_fc_b, ysb, nullptr,
      Mf, DIMC, 128, spe_pos, nullptr, nullptr);

  // ---- transformer blocks ----
  for (int i = 0; i < 2; i++) {
    const float* n1w = blk_n1_w + i * DIMC;
    const float* n1b = blk_n1_b + i * DIMC;
    const float* n2w = blk_n2_w + i * DIMC;
    const float* n2b = blk_n2_b + i * DIMC;
    const u16* qkvW = qkvWb + (size_t)i * 3 * DIMC * DIMC;
    const float* qkvB = blk_qkv_b + (size_t)i * 3 * DIMC;
    const u16* projW = projWb + (size_t)i * DIMC * DIMC;
    const float* projB = blk_proj_b + (size_t)i * DIMC;
    const u16* fc1W = fc1Wb + (size_t)i * DIMC * DIMC;
    const float* fc1B = blk_fc1_b + (size_t)i * DIMC;
    const u16* fc2W = fc2Wb + (size_t)i * DIMC * DIMC;
    const float* fc2B = blk_fc2_b + (size_t)i * DIMC;

    ln_v_k<1><<<M2 / 4, 256, 0, stream>>>(xsc, n1w, n1b, xyin);

    mgemm_k<0><<<dim3(12, M2 / 128), 256, 0, stream>>>(xyin, qkvW, qkvB, qkvxy, nullptr,
        M2, 3 * DIMC, DIMC, nullptr, nullptr, nullptr);

    vt2_k<<<dim3(NHEAD, NB, 2), 256, 0, stream>>>(qkvxy, qkvxy + (size_t)Mx * 3 * DIMC, vtx, vty);

    flashq_k<<<dim3(NHEAD, NB), 256, 0, stream>>>(qkvxy, vtx, oxy, NSPA, 256, 0.125f);
    flashm_k<<<dim3(1, NHEAD, NB), 256, 0, stream>>>(qkvxy + (size_t)Mx * 3 * DIMC, vty,
                                                     oxy + (size_t)Mx * DIMC, NSPE, 64, 0.125f);

    mgemm_k<5><<<dim3(4, M2 / 128), 256, 0, stream>>>(oxy, projW, projB, xsc, clsprj,
        M2, DIMC, DIMC, nullptr, nullptr, nullptr);
    cls_swap_k<<<NB, 256, 0, stream>>>(xsc, clsprj);

    ln_v_k<0><<<M2 / 4, 256, 0, stream>>>(xsc, n2w, n2b, xyin);
    mgemm_k<1><<<dim3(4, M2 / 128), 256, 0, stream>>>(xyin, fc1W, fc1B, qkvxy, nullptr,
        M2, DIMC, DIMC, nullptr, nullptr, nullptr);
    mgemm_k<2><<<dim3(4, M2 / 128), 256, 0, stream>>>(qkvxy, fc2W, fc2B, xsc, nullptr,
        M2, DIMC, DIMC, nullptr, nullptr, nullptr);
  }

  // ---- head (fused LN + classifier) ----
  lnhead_k<<<NB, 256, 0, stream>>>(xsc, ysb, norm1_w, norm1_b, norm2_w, norm2_b,
                                   head_w, head_b, (float*)d_out);
}

// Round 12
// 718.072 us; speedup vs baseline: 1.0182x; 1.0182x over previous
//
#include <hip/hip_runtime.h>
#include <hip/hip_bf16.h>

typedef unsigned short u16;
typedef __attribute__((ext_vector_type(8))) short bf16x8;
typedef __attribute__((ext_vector_type(4))) float f32x4;

#define NB 128
#define BANDS 30
#define HWD 15
#define NPIX 225
#define DIMC 512
#define NHEAD 8
#define HD 64
#define NSPA 226
#define NSPE 31
#define EPSF 1e-5f
#define KCONV 320     // 270 padded to multiple of 64
#define MXROWS 28928  // NB*NSPA
#define MYROWS 3968   // NB*NSPE
#define M2ROWS 32896  // MXROWS+MYROWS

__device__ __forceinline__ float b2f(u16 u) { return __uint_as_float(((unsigned)u) << 16); }
__device__ __forceinline__ u16 f2b(float f) {
  __hip_bfloat16 h = __float2bfloat16(f);
  return *reinterpret_cast<u16*>(&h);
}

#if __has_builtin(__builtin_amdgcn_global_load_lds)
#define HAVE_GLDS 1
__device__ __forceinline__ void gl_lds16(const void* g, void* l) {
  __builtin_amdgcn_global_load_lds((const __attribute__((address_space(1))) void*)g,
                                   (__attribute__((address_space(3))) void*)l, 16, 0, 0);
}
#else
#define HAVE_GLDS 0
#endif

// ---------------- consolidated weight prep ----------------
__global__ __launch_bounds__(256) void prep_k(const float* __restrict__ qkvW,
    const float* __restrict__ projW, const float* __restrict__ fc1W, const float* __restrict__ fc2W,
    const float* __restrict__ fcW, const float* __restrict__ convW,
    const float* __restrict__ g, const float* __restrict__ bb, const float* __restrict__ bm,
    const float* __restrict__ bv, const float* __restrict__ cb,
    u16* __restrict__ qkvWb, u16* __restrict__ projWb, u16* __restrict__ fc1Wb,
    u16* __restrict__ fc2Wb, u16* __restrict__ fcWb, u16* __restrict__ convWb,
    float* __restrict__ sc, float* __restrict__ sh) {
  const int S0 = 2 * 3 * DIMC * DIMC;
  const int S1 = S0 + 2 * DIMC * DIMC;
  const int S2 = S1 + 2 * DIMC * DIMC;
  const int S3 = S2 + 2 * DIMC * DIMC;
  const int S4 = S3 + DIMC * 128;
  const int S5 = S4 + DIMC * KCONV;
  const int S6 = S5 + DIMC;
  for (int i = blockIdx.x * 256 + threadIdx.x; i < S6; i += gridDim.x * 256) {
    if (i < S0) qkvWb[i] = f2b(qkvW[i]);
    else if (i < S1) { int j = i - S0; projWb[j] = f2b(projW[j]); }
    else if (i < S2) { int j = i - S1; fc1Wb[j] = f2b(fc1W[j]); }
    else if (i < S3) { int j = i - S2; fc2Wb[j] = f2b(fc2W[j]); }
    else if (i < S4) { int j = i - S3; fcWb[j] = f2b(fcW[j]); }
    else if (i < S5) {
      int j = i - S4;
      int r = j / KCONV, c = j - r * KCONV;
      convWb[j] = (c < 270) ? f2b(convW[r * 270 + c]) : (u16)0;
    } else {
      int n = i - S5;
      float inv = g[n] * rsqrtf(bv[n] + EPSF);
      sc[n] = inv;
      sh[n] = (cb[n] - bm[n]) * inv + bb[n];
    }
  }
}

// ================= merged stem: cnn_conv (blocks 0..1919) | im2col (next 4500) | cls_init (last 128) =================
#define CNNB 1920   // Mf/2
#define IMCB 4500   // ceil(28800*40/256)
__global__ __launch_bounds__(256) void stem_k(const float* __restrict__ x,
    const float* __restrict__ w, const float* __restrict__ cb, const float* __restrict__ g,
    const float* __restrict__ bb, const float* __restrict__ bm, const float* __restrict__ bv,
    u16* __restrict__ pooled, u16* __restrict__ Ac,
    const float* __restrict__ spa_cls, const float* __restrict__ spe_cls,
    const float* __restrict__ spa_pos, const float* __restrict__ spe_pos,
    u16* __restrict__ xs, u16* __restrict__ ys) {
  __shared__ float img[2][NPIX];
  int blk = blockIdx.x;
  int t = threadIdx.x;
  if (blk < CNNB) {
    // -------- per-band CNN conv + BN + ReLU + mean (2 bands/block) --------
    int b0 = blk * 2;
    for (int idx = t; idx < 2 * NPIX; idx += 256) ((float*)img)[idx] = x[(size_t)b0 * NPIX + idx];
    __syncthreads();
    int half = t >> 7, ch = t & 127;
    const float* im = img[half];
    float inv = g[ch] * rsqrtf(bv[ch] + EPSF);
    float beta = bb[ch] - bm[ch] * inv;
    float w9[9];
#pragma unroll
    for (int q = 0; q < 9; q++) w9[q] = w[ch * 9 + q] * inv;
    float bias = cb[ch] * inv + beta;
    float rm[15], rc[15], rp[15];
#pragma unroll
    for (int j = 0; j < 15; j++) { rm[j] = 0.f; rc[j] = im[j]; }
    float sum = 0.f;
    for (int i = 0; i < 15; i++) {
#pragma unroll
      for (int j = 0; j < 15; j++) rp[j] = (i < 14) ? im[(i + 1) * 15 + j] : 0.f;
      float a[15];
#pragma unroll
      for (int j = 0; j < 15; j++) a[j] = fmaf(w9[4], rc[j], bias);
#pragma unroll
      for (int j = 0; j < 15; j++) {
        if (j > 0)  a[j] = fmaf(w9[3], rc[j - 1], a[j]);
        if (j < 14) a[j] = fmaf(w9[5], rc[j + 1], a[j]);
        a[j] = fmaf(w9[1], rm[j], a[j]);
        if (j > 0)  a[j] = fmaf(w9[0], rm[j - 1], a[j]);
        if (j < 14) a[j] = fmaf(w9[2], rm[j + 1], a[j]);
        a[j] = fmaf(w9[7], rp[j], a[j]);
        if (j > 0)  a[j] = fmaf(w9[6], rp[j - 1], a[j]);
        if (j < 14) a[j] = fmaf(w9[8], rp[j + 1], a[j]);
      }
#pragma unroll
      for (int j = 0; j < 15; j++) sum += fmaxf(a[j], 0.f);
#pragma unroll
      for (int j = 0; j < 15; j++) { rm[j] = rc[j]; rc[j] = rp[j]; }
    }
    pooled[(size_t)(b0 + half) * 128 + ch] = f2b(sum * (1.0f / 225.0f));
  } else if (blk < CNNB + IMCB) {
    // -------- im2col --------
    int idx = (blk - CNNB) * 256 + t;
    if (idx < 28800 * 40) {
      int m = idx / 40, gq = idx - m * 40;
      int b = m / NPIX, p = m - b * NPIX;
      int i = p / 15, j = p - i * 15;
      union { u16 v[8]; uint4 u; } out;
#pragma unroll
      for (int e = 0; e < 8; e++) {
        int c = gq * 8 + e;
        float v = 0.f;
        if (c < 270) {
          int band = c / 9, q = c - band * 9;
          int di = q / 3, dj = q - di * 3;
          int ii = i + di - 1, jj = j + dj - 1;
          if ((unsigned)ii < 15u && (unsigned)jj < 15u)
            v = x[((size_t)b * BANDS + band) * NPIX + ii * 15 + jj];
        }
        out.v[e] = f2b(v);
      }
      *reinterpret_cast<uint4*>(Ac + (size_t)m * KCONV + gq * 8) = out.u;
    }
  } else {
    // -------- cls_init --------
    int b = blk - (CNNB + IMCB);
    int d0 = t, d1 = t + 256;
    xs[(size_t)b * NSPA * DIMC + d0] = f2b(spa_cls[d0] + spa_pos[d0]);
    xs[(size_t)b * NSPA * DIMC + d1] = f2b(spa_cls[d1] + spa_pos[d1]);
    ys[(size_t)b * NSPE * DIMC + d0] = f2b(spe_cls[d0] + spe_pos[d0]);
    ys[(size_t)b * NSPE * DIMC + d1] = f2b(spe_cls[d1] + spe_pos[d1]);
  }
}

// ---------------- LayerNorm, wave-per-row, bf16 spine ----------------
// MODE 0: plain row LN.  MODE 1: LN1 with cross-stream CLS gather.
// MODE 2: LN2 with fused CLS-swap: CLS rows z = 2*spine + clsprj, write z back to spine, LN(z).
template <int MODE>
__global__ __launch_bounds__(256) void ln_v_k(u16* __restrict__ xsc,
    const float* __restrict__ w, const float* __restrict__ bprm, u16* __restrict__ out,
    const u16* __restrict__ clsprj) {
  int wid = threadIdx.x >> 6, lane = threadIdx.x & 63;
  int row = blockIdx.x * 4 + wid;
  const u16* src;
  const u16* clsp = nullptr;
  if (MODE == 1) {
    if (row < MXROWS) {
      int b = row / NSPA, tk = row - b * NSPA;
      src = (tk == 0) ? xsc + ((size_t)MXROWS + (size_t)b * NSPE) * DIMC
                      : xsc + (size_t)row * DIMC;
    } else {
      int ry = row - MXROWS;
      int b = ry / NSPE, tk = ry - b * NSPE;
      src = (tk == 0) ? xsc + (size_t)b * NSPA * DIMC : xsc + (size_t)row * DIMC;
    }
  } else {
    src = xsc + (size_t)row * DIMC;
    if (MODE == 2) {
      if (row < MXROWS) {
        int b = row / NSPA, tk = row - b * NSPA;
        if (tk == 0) clsp = clsprj + (size_t)(128 + b) * DIMC;
      } else {
        int ry = row - MXROWS;
        int b = ry / NSPE, tk = ry - b * NSPE;
        if (tk == 0) clsp = clsprj + (size_t)b * DIMC;
      }
    }
  }
  uint4 av = *reinterpret_cast<const uint4*>(src + lane * 8);
  float f[8];
  f[0] = __uint_as_float(av.x << 16); f[1] = __uint_as_float(av.x & 0xffff0000u);
  f[2] = __uint_as_float(av.y << 16); f[3] = __uint_as_float(av.y & 0xffff0000u);
  f[4] = __uint_as_float(av.z << 16); f[5] = __uint_as_float(av.z & 0xffff0000u);
  f[6] = __uint_as_float(av.w << 16); f[7] = __uint_as_float(av.w & 0xffff0000u);
  if (MODE == 2 && clsp) {
    uint4 cv = *reinterpret_cast<const uint4*>(clsp + lane * 8);
    float c[8];
    c[0] = __uint_as_float(cv.x << 16); c[1] = __uint_as_float(cv.x & 0xffff0000u);
    c[2] = __uint_as_float(cv.y << 16); c[3] = __uint_as_float(cv.y & 0xffff0000u);
    c[4] = __uint_as_float(cv.z << 16); c[5] = __uint_as_float(cv.z & 0xffff0000u);
    c[6] = __uint_as_float(cv.w << 16); c[7] = __uint_as_float(cv.w & 0xffff0000u);
    union { u16 v[8]; uint4 u; } zb;
#pragma unroll
    for (int e = 0; e < 8; e++) {
      f[e] = 2.0f * f[e] + c[e];
      zb.v[e] = f2b(f[e]);
      f[e] = b2f(zb.v[e]);  // match stored precision (prior cls_swap semantics)
    }
    *reinterpret_cast<uint4*>(xsc + (size_t)row * DIMC + lane * 8) = zb.u;
  }
  float s = 0.f, sq = 0.f;
#pragma unroll
  for (int e = 0; e < 8; e++) { s += f[e]; sq += f[e] * f[e]; }
#pragma unroll
  for (int off = 1; off <= 32; off <<= 1) { s += __shfl_xor(s, off); sq += __shfl_xor(sq, off); }
  float mean = s * (1.0f / 512.0f);
  float var = sq * (1.0f / 512.0f) - mean * mean;
  float rstd = rsqrtf(var + EPSF);
  float4 w0 = *reinterpret_cast<const float4*>(w + lane * 8);
  float4 w1 = *reinterpret_cast<const float4*>(w + lane * 8 + 4);
  float4 b0 = *reinterpret_cast<const float4*>(bprm + lane * 8);
  float4 b1 = *reinterpret_cast<const float4*>(bprm + lane * 8 + 4);
  float wv[8] = {w0.x, w0.y, w0.z, w0.w, w1.x, w1.y, w1.z, w1.w};
  float bv2[8] = {b0.x, b0.y, b0.z, b0.w, b1.x, b1.y, b1.z, b1.w};
  union { u16 v[8]; uint4 u; } r;
#pragma unroll
  for (int e = 0; e < 8; e++) r.v[e] = f2b((f[e] - mean) * rstd * wv[e] + bv2[e]);
  *reinterpret_cast<uint4*>(out + (size_t)row * DIMC + lane * 8) = r.u;
}

// ================= 128-tile MFMA GEMM, 16x16x32 core, BK=64, slot-XOR swizzle, XCD-chunked =================
// MODE 0: bf16 o1=acc+bias  MODE 1: bf16 o1=gelu  MODE 2: bf16 o1 += acc+bias (RMW spine)
// MODE 3: conv scatter -> bf16 spine  MODE 4: fc_spe scatter -> bf16 spine
// MODE 5: proj+residual-combine: non-CLS o1 += z (bf16 RMW); CLS rows -> o2 (clsprj)
template <int MODE>
__global__ __launch_bounds__(256) void mgemm_k(const u16* __restrict__ A, const u16* __restrict__ Bw,
    const float* __restrict__ bias, u16* o1, u16* o2, int M, int N, int K,
    const float* aux0, const float* aux1, const float* aux2) {
  __shared__ u16 As[128 * 64];
  __shared__ u16 Bs[128 * 64];
  const int t = threadIdx.x;
  const int wid = t >> 6, l = t & 63;
  const int wm = wid >> 1, wn = wid & 1;
  const int fr = l & 15, kg = l >> 4;

  const int nx = gridDim.x, nwg = nx * gridDim.y;
  int hlin = blockIdx.y * nx + blockIdx.x;
  int xcd = hlin & 7, j = hlin >> 3;
  int q8 = nwg >> 3, r8 = nwg & 7;
  int L = (xcd < r8 ? xcd * (q8 + 1) : r8 * (q8 + 1) + (xcd - r8) * q8) + j;
  const int n0 = (L % nx) * 128, m0 = (L / nx) * 128;

  const int srow = l >> 3;
  const int sslot = l & 7;

  f32x4 acc[4][4];
#pragma unroll
  for (int i = 0; i < 4; i++)
#pragma unroll
    for (int j2 = 0; j2 < 4; j2++) acc[i][j2] = (f32x4){0.f, 0.f, 0.f, 0.f};

  for (int kq = 0; kq < K; kq += 64) {
#if !HAVE_GLDS
    uint4 ra[4], rb[4];
#pragma unroll
    for (int i = 0; i < 4; i++) {
      int r = wid * 32 + i * 8 + srow;
      int cg = sslot ^ (r & 7);
      ra[i] = *reinterpret_cast<const uint4*>(A + (size_t)(m0 + r) * K + kq + cg * 8);
      rb[i] = *reinterpret_cast<const uint4*>(Bw + (size_t)(n0 + r) * K + kq + cg * 8);
    }
#endif
    __syncthreads();
#if HAVE_GLDS
#pragma unroll
    for (int i = 0; i < 4; i++) {
      int r = wid * 32 + i * 8 + srow;
      int cg = sslot ^ (r & 7);
      gl_lds16(A + (size_t)(m0 + r) * K + kq + cg * 8, &As[(wid * 32 + i * 8) * 64]);
      gl_lds16(Bw + (size_t)(n0 + r) * K + kq + cg * 8, &Bs[(wid * 32 + i * 8) * 64]);
    }
#else
#pragma unroll
    for (int i = 0; i < 4; i++) {
      int r = wid * 32 + i * 8 + srow;
      *reinterpret_cast<uint4*>(&As[r * 64 + sslot * 8]) = ra[i];
      *reinterpret_cast<uint4*>(&Bs[r * 64 + sslot * 8]) = rb[i];
    }
#endif
    __syncthreads();
#pragma unroll
    for (int h = 0; h < 2; h++) {
      bf16x8 af[4], bfr[4];
#pragma unroll
      for (int mi = 0; mi < 4; mi++) {
        int r = wm * 64 + mi * 16 + fr;
        af[mi] = *reinterpret_cast<const bf16x8*>(&As[r * 64 + (((h * 4 + kg) ^ (fr & 7)) * 8)]);
      }
#pragma unroll
      for (int nj = 0; nj < 4; nj++) {
        int n = wn * 64 + nj * 16 + fr;
        bfr[nj] = *reinterpret_cast<const bf16x8*>(&Bs[n * 64 + (((h * 4 + kg) ^ (fr & 7)) * 8)]);
      }
#pragma unroll
      for (int mi = 0; mi < 4; mi++)
#pragma unroll
        for (int nj = 0; nj < 4; nj++)
          acc[mi][nj] = __builtin_amdgcn_mfma_f32_16x16x32_bf16(af[mi], bfr[nj], acc[mi][nj], 0, 0, 0);
    }
  }

#pragma unroll
  for (int mi = 0; mi < 4; mi++) {
#pragma unroll
    for (int q = 0; q < 4; q++) {
      int m = m0 + wm * 64 + mi * 16 + kg * 4 + q;
#pragma unroll
      for (int nj = 0; nj < 4; nj++) {
        int n = n0 + wn * 64 + nj * 16 + fr;
        float v = acc[mi][nj][q];
        if (MODE == 0) {
          o1[(size_t)m * N + n] = f2b(v + bias[n]);
        } else if (MODE == 1) {
          float z = v + bias[n];
          o1[(size_t)m * N + n] = f2b(0.5f * z * (1.0f + erff(z * 0.70710678118f)));
        } else if (MODE == 2) {
          size_t idx = (size_t)m * N + n;
          o1[idx] = f2b(b2f(o1[idx]) + v + bias[n]);
        } else if (MODE == 3) {
          int b = m / NPIX, p = m - b * NPIX;
          float z = fmaxf(v * aux0[n] + aux1[n], 0.f) + aux2[(size_t)(p + 1) * DIMC + n];
          o1[((size_t)b * NSPA + p + 1) * DIMC + n] = f2b(z);
        } else if (MODE == 4) {
          int b = m / BANDS, band = m - b * BANDS;
          float z = fmaxf(v + bias[n], 0.f) + aux0[(size_t)(band + 1) * DIMC + n];
          o1[((size_t)b * NSPE + band + 1) * DIMC + n] = f2b(z);
        } else if (MODE == 5) {
          float z = v + bias[n];
          int tk, sidx;
          if (m < MXROWS) {
            int b = m / NSPA; tk = m - b * NSPA; sidx = b;
          } else {
            int ry = m - MXROWS; int b = ry / NSPE; tk = ry - b * NSPE; sidx = 128 + b;
          }
          if (tk == 0) {
            o2[(size_t)sidx * DIMC + n] = f2b(z);
          } else {
            size_t idx = (size_t)m * N + n;
            o1[idx] = f2b(b2f(o1[idx]) + z);
          }
        }
      }
    }
  }
}

// ================= V transpose, both streams in one launch =================
__global__ __launch_bounds__(256) void vt2_k(const u16* __restrict__ qkv_spa,
    const u16* __restrict__ qkv_spe, u16* __restrict__ vtx, u16* __restrict__ vty) {
  __shared__ u16 Vl[64 * 72];
  int h = blockIdx.x, b = blockIdx.y, strm = blockIdx.z;
  int NTOK = strm ? NSPE : NSPA;
  int KP = strm ? 64 : 256;
  int t = threadIdx.x;
  const size_t rs = 3 * DIMC;
  const u16* src = (strm ? qkv_spe : qkv_spa) + (size_t)b * NTOK * rs + 2 * DIMC + h * HD;
  u16* dst = (strm ? vty : vtx) + (size_t)(b * NHEAD + h) * HD * KP;
  for (int kt = 0; kt < KP / 64; kt++) {
    __syncthreads();
#pragma unroll
    for (int p = 0; p < 2; p++) {
      int idx = p * 256 + t;
      int row = idx >> 3, c = idx & 7;
      int tok = kt * 64 + row;
      uint4 v = make_uint4(0, 0, 0, 0);
      if (tok < NTOK) v = *reinterpret_cast<const uint4*>(src + (size_t)tok * rs + c * 8);
      *reinterpret_cast<uint4*>(&Vl[row * 72 + c * 8]) = v;
    }
    __syncthreads();
    int d = t & 63, tg = t >> 6;
    unsigned pu[8];
#pragma unroll
    for (int i = 0; i < 8; i++) {
      unsigned a = Vl[(tg * 16 + 2 * i) * 72 + d];
      unsigned bb2 = Vl[(tg * 16 + 2 * i + 1) * 72 + d];
      pu[i] = (bb2 << 16) | a;
    }
    uint4 o0 = make_uint4(pu[0], pu[1], pu[2], pu[3]);
    uint4 o1 = make_uint4(pu[4], pu[5], pu[6], pu[7]);
    u16* dp = dst + (size_t)d * KP + kt * 64 + tg * 16;
    *reinterpret_cast<uint4*>(dp) = o0;
    *reinterpret_cast<uint4*>(dp + 8) = o1;
  }
}

// ================= shared helpers for flash =================
__device__ __forceinline__ int fsw(int row, int chunk) {
  return row * 64 + ((chunk ^ (row & 7)) << 3);
}
__device__ __forceinline__ void stage64(const u16* __restrict__ gsrc, size_t gstride,
                                        u16* lds, int w, int l) {
#pragma unroll
  for (int i = 0; i < 2; i++) {
    int r = w * 16 + i * 8 + (l >> 3);
    int c = l & 7;
    int scg = c ^ (r & 7);
    const u16* g = gsrc + (size_t)r * gstride + scg * 8;
#if HAVE_GLDS
    gl_lds16(g, &lds[(w * 16 + i * 8) * 64]);
#else
    *reinterpret_cast<uint4*>(&lds[r * 64 + c * 8]) = *reinterpret_cast<const uint4*>(g);
#endif
  }
}

// ================= flashq: spa attention, wave owns a 64-row q-tile =================
__global__ __launch_bounds__(256) void flashq_k(const u16* __restrict__ qkv,
    const u16* __restrict__ vt, u16* __restrict__ o, int N, int kpad, float scale) {
  __shared__ u16 Qs[4][64 * 64];
  __shared__ u16 KV[2][64 * 64];
  u16* Ks = KV[0];
  u16* Vs = KV[1];
  u16* Ol = KV[0];
  const int h = blockIdx.x, b = blockIdx.y;
  const int t = threadIdx.x;
  const int w = t >> 6, l = t & 63;
  const int lr = l & 15, lk = l >> 4;
  const size_t rs = 3 * DIMC;
  const size_t qbase = (size_t)b * N * rs + h * HD;
  const u16* vbase = vt + (size_t)(b * NHEAD + h) * HD * kpad;

#pragma unroll
  for (int i = 0; i < 8; i++) {
    int r = i * 8 + (l >> 3);
    int c = l & 7;
    int scg = c ^ (r & 7);
    const u16* g = qkv + qbase + (size_t)(w * 64 + r) * rs + scg * 8;
#if HAVE_GLDS
    gl_lds16(g, &Qs[w][(i * 8) * 64]);
#else
    *reinterpret_cast<uint4*>(&Qs[w][r * 64 + c * 8]) = *reinterpret_cast<const uint4*>(g);
#endif
  }
  __syncthreads();
  bf16x8 bq[4][2];
#pragma unroll
  for (int nj = 0; nj < 4; nj++) {
    bq[nj][0] = *reinterpret_cast<const bf16x8*>(&Qs[w][fsw(nj * 16 + lr, lk)]);
    bq[nj][1] = *reinterpret_cast<const bf16x8*>(&Qs[w][fsw(nj * 16 + lr, 4 + lk)]);
  }

  float m_i[4], l_i[4];
  f32x4 oacc[4][4];
#pragma unroll
  for (int nj = 0; nj < 4; nj++) { m_i[nj] = -1e30f; l_i[nj] = 0.f; }
#pragma unroll
  for (int mi = 0; mi < 4; mi++)
#pragma unroll
    for (int nj = 0; nj < 4; nj++) oacc[mi][nj] = (f32x4){0.f, 0.f, 0.f, 0.f};

  const int nkt = kpad >> 6;
  for (int kt = 0; kt < nkt; kt++) {
    __syncthreads();
    stage64(qkv + qbase + DIMC + (size_t)(kt * 64) * rs, rs, Ks, w, l);
    stage64(vbase + kt * 64, (size_t)kpad, Vs, w, l);
    __syncthreads();

#pragma unroll
    for (int nj = 0; nj < 4; nj++) {
      f32x4 st[4];
#pragma unroll
      for (int mi = 0; mi < 4; mi++) st[mi] = (f32x4){0.f, 0.f, 0.f, 0.f};
      __builtin_amdgcn_s_setprio(1);
#pragma unroll
      for (int mi = 0; mi < 4; mi++) {
        bf16x8 ak0 = *reinterpret_cast<const bf16x8*>(&Ks[fsw(mi * 16 + lr, lk)]);
        bf16x8 ak1 = *reinterpret_cast<const bf16x8*>(&Ks[fsw(mi * 16 + lr, 4 + lk)]);
        st[mi] = __builtin_amdgcn_mfma_f32_16x16x32_bf16(ak0, bq[nj][0], st[mi], 0, 0, 0);
        st[mi] = __builtin_amdgcn_mfma_f32_16x16x32_bf16(ak1, bq[nj][1], st[mi], 0, 0, 0);
      }
      __builtin_amdgcn_s_setprio(0);

      float sv[4][4];
      float tmax = -1e30f;
#pragma unroll
      for (int mi = 0; mi < 4; mi++)
#pragma unroll
        for (int q = 0; q < 4; q++) {
          int kgl = kt * 64 + mi * 16 + lk * 4 + q;
          float v = (kgl < N) ? st[mi][q] * scale : -1e30f;
          sv[mi][q] = v;
          tmax = fmaxf(tmax, v);
        }
      tmax = fmaxf(tmax, __shfl_xor(tmax, 16));
      tmax = fmaxf(tmax, __shfl_xor(tmax, 32));
      float mn = fmaxf(m_i[nj], tmax);
      float corr = __expf(m_i[nj] - mn);
      m_i[nj] = mn;
      float rsum = 0.f;
#pragma unroll
      for (int mi = 0; mi < 4; mi++)
#pragma unroll
        for (int q = 0; q < 4; q++) {
          float p = __expf(sv[mi][q] - mn);
          sv[mi][q] = p;
          rsum += p;
        }
      rsum += __shfl_xor(rsum, 16);
      rsum += __shfl_xor(rsum, 32);
      l_i[nj] = l_i[nj] * corr + rsum;
#pragma unroll
      for (int mi = 0; mi < 4; mi++) oacc[mi][nj] *= corr;

      unsigned pk[4][2];
#pragma unroll
      for (int mi = 0; mi < 4; mi++) {
        pk[mi][0] = ((unsigned)f2b(sv[mi][1]) << 16) | (unsigned)f2b(sv[mi][0]);
        pk[mi][1] = ((unsigned)f2b(sv[mi][3]) << 16) | (unsigned)f2b(sv[mi][2]);
      }
      int src0 = lr + 32 * (lk & 1);
      int src1 = src0 + 16;
      bool hi = lk >= 2;
      bf16x8 pbv[2];
#pragma unroll
      for (int c = 0; c < 2; c++) {
        unsigned a0 = __shfl(pk[2 * c][0], src0), b0 = __shfl(pk[2 * c + 1][0], src0);
        unsigned a1 = __shfl(pk[2 * c][1], src0), b1 = __shfl(pk[2 * c + 1][1], src0);
        unsigned a2 = __shfl(pk[2 * c][0], src1), b2 = __shfl(pk[2 * c + 1][0], src1);
        unsigned a3 = __shfl(pk[2 * c][1], src1), b3 = __shfl(pk[2 * c + 1][1], src1);
        union { unsigned u[4]; bf16x8 v; } pu;
        pu.u[0] = hi ? b0 : a0;
        pu.u[1] = hi ? b1 : a1;
        pu.u[2] = hi ? b2 : a2;
        pu.u[3] = hi ? b3 : a3;
        pbv[c] = pu.v;
      }

      __builtin_amdgcn_s_setprio(1);
#pragma unroll
      for (int mi = 0; mi < 4; mi++) {
        bf16x8 av0 = *reinterpret_cast<const bf16x8*>(&Vs[fsw(mi * 16 + lr, lk)]);
        bf16x8 av1 = *reinterpret_cast<const bf16x8*>(&Vs[fsw(mi * 16 + lr, 4 + lk)]);
        oacc[mi][nj] = __builtin_amdgcn_mfma_f32_16x16x32_bf16(av0, pbv[0], oacc[mi][nj], 0, 0, 0);
        oacc[mi][nj] = __builtin_amdgcn_mfma_f32_16x16x32_bf16(av1, pbv[1], oacc[mi][nj], 0, 0, 0);
      }
      __builtin_amdgcn_s_setprio(0);
    }
  }

  float invl[4];
#pragma unroll
  for (int nj = 0; nj < 4; nj++) invl[nj] = 1.0f / l_i[nj];
  for (int pass = 0; pass < 4; pass++) {
    __syncthreads();
    if (w == pass) {
#pragma unroll
      for (int mi = 0; mi < 4; mi++)
#pragma unroll
        for (int nj = 0; nj < 4; nj++) {
          unsigned lo = ((unsigned)f2b(oacc[mi][nj][1] * invl[nj]) << 16) |
                        (unsigned)f2b(oacc[mi][nj][0] * invl[nj]);
          unsigned hi2 = ((unsigned)f2b(oacc[mi][nj][3] * invl[nj]) << 16) |
                         (unsigned)f2b(oacc[mi][nj][2] * invl[nj]);
          uint2 pr; pr.x = lo; pr.y = hi2;
          *reinterpret_cast<uint2*>(&Ol[(nj * 16 + lr) * 72 + mi * 16 + lk * 4]) = pr;
        }
    }
    __syncthreads();
    int row = t >> 2, c4 = t & 3;
    int qrow = pass * 64 + row;
    if (qrow < N) {
      uint4 v0 = *reinterpret_cast<const uint4*>(&Ol[row * 72 + c4 * 8]);
      uint4 v1 = *reinterpret_cast<const uint4*>(&Ol[row * 72 + (c4 + 4) * 8]);
      u16* op = o + ((size_t)b * N + qrow) * DIMC + h * HD;
      *reinterpret_cast<uint4*>(op + c4 * 8) = v0;
      *reinterpret_cast<uint4*>(op + (c4 + 4) * 8) = v1;
    }
  }
}

// ================= flashm: spe attention =================
__global__ __launch_bounds__(256) void flashm_k(const u16* __restrict__ qkv,
    const u16* __restrict__ vt, u16* __restrict__ o, int N, int kpad, float scale) {
  __shared__ u16 Qs[64 * 64], Ks[64 * 64], Vs[64 * 64];
  __shared__ u16 Ol[64 * 72];
  const int qt = blockIdx.x, h = blockIdx.y, b = blockIdx.z;
  const int t = threadIdx.x;
  const int w = t >> 6, l = t & 63;
  const int lr = l & 15, lk = l >> 4;
  const size_t rs = 3 * DIMC;
  const size_t qbase = (size_t)b * N * rs + h * HD;
  const u16* vbase = vt + (size_t)(b * NHEAD + h) * HD * kpad;

  stage64(qkv + qbase + (size_t)(qt * 64) * rs, rs, Qs, w, l);
  __syncthreads();
  bf16x8 bq0 = *reinterpret_cast<const bf16x8*>(&Qs[fsw(w * 16 + lr, lk)]);
  bf16x8 bq1 = *reinterpret_cast<const bf16x8*>(&Qs[fsw(w * 16 + lr, 4 + lk)]);

  float m_i = -1e30f, l_i = 0.f;
  f32x4 oacc[4];
#pragma unroll
  for (int mi = 0; mi < 4; mi++) oacc[mi] = (f32x4){0.f, 0.f, 0.f, 0.f};

  const int nkt = (kpad + 63) >> 6;
  for (int kt = 0; kt < nkt; kt++) {
    __syncthreads();
    stage64(qkv + qbase + DIMC + (size_t)(kt * 64) * rs, rs, Ks, w, l);
    stage64(vbase + kt * 64, (size_t)kpad, Vs, w, l);
    __syncthreads();

    f32x4 st[4];
#pragma unroll
    for (int mi = 0; mi < 4; mi++) st[mi] = (f32x4){0.f, 0.f, 0.f, 0.f};
#pragma unroll
    for (int mi = 0; mi < 4; mi++) {
      bf16x8 ak0 = *reinterpret_cast<const bf16x8*>(&Ks[fsw(mi * 16 + lr, lk)]);
      bf16x8 ak1 = *reinterpret_cast<const bf16x8*>(&Ks[fsw(mi * 16 + lr, 4 + lk)]);
      st[mi] = __builtin_amdgcn_mfma_f32_16x16x32_bf16(ak0, bq0, st[mi], 0, 0, 0);
      st[mi] = __builtin_amdgcn_mfma_f32_16x16x32_bf16(ak1, bq1, st[mi], 0, 0, 0);
    }

    float sv[4][4];
    float tmax = -1e30f;
#pragma unroll
    for (int mi = 0; mi < 4; mi++)
#pragma unroll
      for (int q = 0; q < 4; q++) {
        int kgl = kt * 64 + mi * 16 + lk * 4 + q;
        float v = (kgl < N) ? st[mi][q] * scale : -1e30f;
        sv[mi][q] = v;
        tmax = fmaxf(tmax, v);
      }
    tmax = fmaxf(tmax, __shfl_xor(tmax, 16));
    tmax = fmaxf(tmax, __shfl_xor(tmax, 32));
    float mn = fmaxf(m_i, tmax);
    float corr = __expf(m_i - mn);
    m_i = mn;
    float rsum = 0.f;
#pragma unroll
    for (int mi = 0; mi < 4; mi++)
#pragma unroll
      for (int q = 0; q < 4; q++) {
        float p = __expf(sv[mi][q] - mn);
        sv[mi][q] = p;
        rsum += p;
      }
    rsum += __shfl_xor(rsum, 16);
    rsum += __shfl_xor(rsum, 32);
    l_i = l_i * corr + rsum;
#pragma unroll
    for (int mi = 0; mi < 4; mi++) oacc[mi] *= corr;

    unsigned pk[4][2];
#pragma unroll
    for (int mi = 0; mi < 4; mi++) {
      pk[mi][0] = ((unsigned)f2b(sv[mi][1]) << 16) | (unsigned)f2b(sv[mi][0]);
      pk[mi][1] = ((unsigned)f2b(sv[mi][3]) << 16) | (unsigned)f2b(sv[mi][2]);
    }
    int src0 = lr + 32 * (lk & 1);
    int src1 = src0 + 16;
    bool hi = lk >= 2;
    bf16x8 pbv[2];
#pragma unroll
    for (int c = 0; c < 2; c++) {
      unsigned a0 = __shfl(pk[2 * c][0], src0), b0 = __shfl(pk[2 * c + 1][0], src0);
      unsigned a1 = __shfl(pk[2 * c][1], src0), b1 = __shfl(pk[2 * c + 1][1], src0);
      unsigned a2 = __shfl(pk[2 * c][0], src1), b2 = __shfl(pk[2 * c + 1][0], src1);
      unsigned a3 = __shfl(pk[2 * c][1], src1), b3 = __shfl(pk[2 * c + 1][1], src1);
      union { unsigned u[4]; bf16x8 v; } pu;
      pu.u[0] = hi ? b0 : a0;
      pu.u[1] = hi ? b1 : a1;
      pu.u[2] = hi ? b2 : a2;
      pu.u[3] = hi ? b3 : a3;
      pbv[c] = pu.v;
    }

#pragma unroll
    for (int mi = 0; mi < 4; mi++) {
      bf16x8 av0 = *reinterpret_cast<const bf16x8*>(&Vs[fsw(mi * 16 + lr, lk)]);
      bf16x8 av1 = *reinterpret_cast<const bf16x8*>(&Vs[fsw(mi * 16 + lr, 4 + lk)]);
      oacc[mi] = __builtin_amdgcn_mfma_f32_16x16x32_bf16(av0, pbv[0], oacc[mi], 0, 0, 0);
      oacc[mi] = __builtin_amdgcn_mfma_f32_16x16x32_bf16(av1, pbv[1], oacc[mi], 0, 0, 0);
    }
  }

  float invl = 1.0f / l_i;
#pragma unroll
  for (int mi = 0; mi < 4; mi++) {
    unsigned lo = ((unsigned)f2b(oacc[mi][1] * invl) << 16) | (unsigned)f2b(oacc[mi][0] * invl);
    unsigned hi2 = ((unsigned)f2b(oacc[mi][3] * invl) << 16) | (unsigned)f2b(oacc[mi][2] * invl);
    uint2 pr; pr.x = lo; pr.y = hi2;
    *reinterpret_cast<uint2*>(&Ol[(w * 16 + lr) * 72 + mi * 16 + lk * 4]) = pr;
  }
  __syncthreads();
  {
    int row = t >> 2, c4 = t & 3;
    int qrow = qt * 64 + row;
    if (qrow < N) {
      uint4 v0 = *reinterpret_cast<const uint4*>(&Ol[row * 72 + c4 * 8]);
      uint4 v1 = *reinterpret_cast<const uint4*>(&Ol[row * 72 + (c4 + 4) * 8]);
      u16* op = o + ((size_t)b * N + qrow) * DIMC + h * HD;
      *reinterpret_cast<uint4*>(op + c4 * 8) = v0;
      *reinterpret_cast<uint4*>(op + (c4 + 4) * 8) = v1;
    }
  }
}

// ---------------- fused final LN (CLS tokens, bf16 spine) + head ----------------
__global__ __launch_bounds__(256) void lnhead_k(const u16* __restrict__ xsc,
    const u16* __restrict__ ysb, const float* __restrict__ w1, const float* __restrict__ b1,
    const float* __restrict__ w2, const float* __restrict__ b2, const float* __restrict__ hw,
    const float* __restrict__ hb, float* __restrict__ out) {
  __shared__ float cl[1024];
  __shared__ float sa[4], sb4[4];
  __shared__ float part[256];
  int b = blockIdx.x, t = threadIdx.x;
  int wid = t >> 6;
  for (int half = 0; half < 2; half++) {
    const u16* src = half ? (ysb + (size_t)b * NSPE * DIMC) : (xsc + (size_t)b * NSPA * DIMC);
    const float* w = half ? w2 : w1;
    const float* bp = half ? b2 : b1;
    float x0 = b2f(src[t]), x1 = b2f(src[t + 256]);
    float s = x0 + x1, sq = x0 * x0 + x1 * x1;
    for (int off = 32; off; off >>= 1) { s += __shfl_down(s, off); sq += __shfl_down(sq, off); }
    if ((t & 63) == 0) { sa[wid] = s; sb4[wid] = sq; }
    __syncthreads();
    s = sa[0] + sa[1] + sa[2] + sa[3];
    sq = sb4[0] + sb4[1] + sb4[2] + sb4[3];
    float mean = s * (1.0f / 512.0f);
    float var = sq * (1.0f / 512.0f) - mean * mean;
    float rstd = rsqrtf(var + EPSF);
    cl[half * DIMC + t] = (x0 - mean) * rstd * w[t] + bp[t];
    cl[half * DIMC + t + 256] = (x1 - mean) * rstd * w[t + 256] + bp[t + 256];
    __syncthreads();
  }
  int c = t >> 4, sl = t & 15;
  float p = 0.f;
  for (int j = 0; j < 64; j++) p += cl[sl * 64 + j] * hw[(size_t)c * 1024 + sl * 64 + j];
  part[t] = p;
  __syncthreads();
  if (sl == 0) {
    float sum = hb[c];
    for (int q = 0; q < 16; q++) sum += part[c * 16 + q];
    out[(size_t)b * 16 + c] = sum;
  }
}

extern "C" void kernel_launch(void* const* d_in, const int* in_sizes, int n_in,
                              void* d_out, int out_size, void* d_ws, size_t ws_size,
                              hipStream_t stream) {
  const float* x        = (const float*)d_in[0];
  const float* conv_h_w = (const float*)d_in[1];
  const float* conv_h_b = (const float*)d_in[2];
  const float* bn_h_g   = (const float*)d_in[3];
  const float* bn_h_b   = (const float*)d_in[4];
  const float* bn_h_m   = (const float*)d_in[5];
  const float* bn_h_v   = (const float*)d_in[6];
  const float* cnn_conv_w = (const float*)d_in[7];
  const float* cnn_conv_b = (const float*)d_in[8];
  const float* cnn_bn_g = (const float*)d_in[9];
  const float* cnn_bn_b = (const float*)d_in[10];
  const float* cnn_bn_m = (const float*)d_in[11];
  const float* cnn_bn_v = (const float*)d_in[12];
  const float* cnn_fc_w = (const float*)d_in[13];
  const float* cnn_fc_b = (const float*)d_in[14];
  const float* spa_cls  = (const float*)d_in[15];
  const float* spe_cls  = (const float*)d_in[16];
  const float* spa_pos  = (const float*)d_in[17];
  const float* spe_pos  = (const float*)d_in[18];
  const float* blk_n1_w = (const float*)d_in[19];
  const float* blk_n1_b = (const float*)d_in[20];
  const float* blk_n2_w = (const float*)d_in[21];
  const float* blk_n2_b = (const float*)d_in[22];
  const float* blk_qkv_w = (const float*)d_in[23];
  const float* blk_qkv_b = (const float*)d_in[24];
  const float* blk_proj_w = (const float*)d_in[25];
  const float* blk_proj_b = (const float*)d_in[26];
  const float* blk_fc1_w = (const float*)d_in[27];
  const float* blk_fc1_b = (const float*)d_in[28];
  const float* blk_fc2_w = (const float*)d_in[29];
  const float* blk_fc2_b = (const float*)d_in[30];
  const float* norm1_w  = (const float*)d_in[31];
  const float* norm1_b  = (const float*)d_in[32];
  const float* norm2_w  = (const float*)d_in[33];
  const float* norm2_b  = (const float*)d_in[34];
  const float* head_w   = (const float*)d_in[35];
  const float* head_b   = (const float*)d_in[36];

  char* ws = (char*)d_ws;
  size_t off = 0;
  auto take = [&](size_t bytes) -> char* {
    char* p = ws + off;
    off = (off + bytes + 255) & ~(size_t)255;
    return p;
  };
  const int Mx = MXROWS, M2 = M2ROWS;
  const int Mc = NB * NPIX;   // 28800
  const int Mf = NB * BANDS;  // 3840
  u16* xsc    = (u16*)take((size_t)M2 * DIMC * 2);      // bf16 residual spine (xs||ys)
  u16* ysb    = xsc + (size_t)Mx * DIMC;
  u16* xyin   = (u16*)take((size_t)M2 * DIMC * 2);      // LN out; vtx overlays during attention
  u16* qkvxy  = (u16*)take((size_t)M2 * 3 * DIMC * 2);
  u16* oxy    = (u16*)take((size_t)M2 * DIMC * 2);
  u16* clsprj = (u16*)take((size_t)256 * DIMC * 2);
  u16* pooled = (u16*)take((size_t)Mf * 128 * 2);
  u16* qkvWb  = (u16*)take((size_t)2 * 3 * DIMC * DIMC * 2);
  u16* projWb = (u16*)take((size_t)2 * DIMC * DIMC * 2);
  u16* fc1Wb  = (u16*)take((size_t)2 * DIMC * DIMC * 2);
  u16* fc2Wb  = (u16*)take((size_t)2 * DIMC * DIMC * 2);
  u16* fcWb   = (u16*)take((size_t)DIMC * 128 * 2);
  u16* convWb = (u16*)take((size_t)DIMC * KCONV * 2);
  float* bnsc = (float*)take(DIMC * 4);
  float* bnsh = (float*)take(DIMC * 4);
  u16* vty    = (u16*)take((size_t)NB * NHEAD * HD * 64 * 2);  // 8.4MB
  u16* Acol   = qkvxy;   // 18.4MB << qkvxy
  u16* vtx    = xyin;    // 33.55MB <= xyin; xyin dead between qkv-GEMM and LN2

  // ---- weight prep (single consolidated launch) ----
  prep_k<<<2048, 256, 0, stream>>>(blk_qkv_w, blk_proj_w, blk_fc1_w, blk_fc2_w, cnn_fc_w,
      conv_h_w, bn_h_g, bn_h_b, bn_h_m, bn_h_v, conv_h_b,
      qkvWb, projWb, fc1Wb, fc2Wb, fcWb, convWb, bnsc, bnsh);

  // ---- merged stem (cnn_conv | im2col | cls_init) ----
  stem_k<<<CNNB + IMCB + NB, 256, 0, stream>>>(x, cnn_conv_w, cnn_conv_b, cnn_bn_g, cnn_bn_b,
      cnn_bn_m, cnn_bn_v, pooled, Acol, spa_cls, spe_cls, spa_pos, spe_pos, xsc, ysb);
  mgemm_k<3><<<dim3(4, Mc / 128), 256, 0, stream>>>(Acol, convWb, nullptr, xsc, nullptr,
      Mc, DIMC, KCONV, bnsc, bnsh, spa_pos);
  mgemm_k<4><<<dim3(4, Mf / 128), 256, 0, stream>>>(pooled, fcWb, cnn_fc_b, ysb, nullptr,
      Mf, DIMC, 128, spe_pos, nullptr, nullptr);

  // ---- transformer blocks ----
  for (int i = 0; i < 2; i++) {
    const float* n1w = blk_n1_w + i * DIMC;
    const float* n1b = blk_n1_b + i * DIMC;
    const float* n2w = blk_n2_w + i * DIMC;
    const float* n2b = blk_n2_b + i * DIMC;
    const u16* qkvW = qkvWb + (size_t)i * 3 * DIMC * DIMC;
    const float* qkvB = blk_qkv_b + (size_t)i * 3 * DIMC;
    const u16* projW = projWb + (size_t)i * DIMC * DIMC;
    const float* projB = blk_proj_b + (size_t)i * DIMC;
    const u16* fc1W = fc1Wb + (size_t)i * DIMC * DIMC;
    const float* fc1B = blk_fc1_b + (size_t)i * DIMC;
    const u16* fc2W = fc2Wb + (size_t)i * DIMC * DIMC;
    const float* fc2B = blk_fc2_b + (size_t)i * DIMC;

    ln_v_k<1><<<M2 / 4, 256, 0, stream>>>(xsc, n1w, n1b, xyin, nullptr);

    mgemm_k<0><<<dim3(12, M2 / 128), 256, 0, stream>>>(xyin, qkvW, qkvB, qkvxy, nullptr,
        M2, 3 * DIMC, DIMC, nullptr, nullptr, nullptr);

    vt2_k<<<dim3(NHEAD, NB, 2), 256, 0, stream>>>(qkvxy, qkvxy + (size_t)Mx * 3 * DIMC, vtx, vty);

    flashq_k<<<dim3(NHEAD, NB), 256, 0, stream>>>(qkvxy, vtx, oxy, NSPA, 256, 0.125f);
    flashm_k<<<dim3(1, NHEAD, NB), 256, 0, stream>>>(qkvxy + (size_t)Mx * 3 * DIMC, vty,
                                                     oxy + (size_t)Mx * DIMC, NSPE, 64, 0.125f);

    mgemm_k<5><<<dim3(4, M2 / 128), 256, 0, stream>>>(oxy, projW, projB, xsc, clsprj,
        M2, DIMC, DIMC, nullptr, nullptr, nullptr);

    ln_v_k<2><<<M2 / 4, 256, 0, stream>>>(xsc, n2w, n2b, xyin, clsprj);
    mgemm_k<1><<<dim3(4, M2 / 128), 256, 0, stream>>>(xyin, fc1W, fc1B, qkvxy, nullptr,
        M2, DIMC, DIMC, nullptr, nullptr, nullptr);
    mgemm_k<2><<<dim3(4, M2 / 128), 256, 0, stream>>>(qkvxy, fc2W, fc2B, xsc, nullptr,
        M2, DIMC, DIMC, nullptr, nullptr, nullptr);
  }

  // ---- head (fused LN + classifier) ----
  lnhead_k<<<NB, 256, 0, stream>>>(xsc, ysb, norm1_w, norm1_b, norm2_w, norm2_b,
                                   head_w, head_b, (float*)d_out);
}